// Round 17
// baseline (84.961 us; speedup 1.0000x reference)
//
#include <hip/hip_runtime.h>

#define NB 16        // molecules
#define NA 2048      // atoms per molecule
#define BLOCK 256
#define JL 8         // j lane-groups per block
#define JT 4         // j atoms per thread
#define JB (JL*JT)   // 32 j atoms per block
#define SPLIT 32     // i-interleave slots (= BLOCK/JL)
#define RSTRIDE 33   // padded reduction row stride (conflict-free)

__global__ void zero_pot_kernel(float* out) {
    if (threadIdx.x < NB) out[threadIdx.x] = 0.0f;
}

// Pure-VALU rsqrt: bit-trick seed + 2 Newton iterations (rel err ~4.5e-6).
// Avoids v_rsq_f32 -> the transcendental pipe (~64 cyc/wave) that R3..R16
// fitting identifies as the throughput wall at 1 trans/pair.
__device__ __forceinline__ float fast_rsqrt(float x) {
    float h = 0.5f * x;
    int i = 0x5f3759df - (__float_as_int(x) >> 1);
    float y = __int_as_float(i);
    y = y * fmaf(-h, y * y, 1.5f);   // Newton 1: err ~1.7e-3
    y = y * fmaf(-h, y * y, 1.5f);   // Newton 2: err ~4.5e-6
    return y;
}

__global__ __launch_bounds__(BLOCK) void coulomb_kernel(
    const float* __restrict__ pos,   // [NB*NA, 3]
    const float* __restrict__ q,     // [NB*NA, 1]
    float* __restrict__ out)         // [NB + NB*NA]
{
    __shared__ float4 sp4[NA];              // 32 KB: {x,y,z,q} per atom
    __shared__ float red[SPLIT * RSTRIDE];  // 4.2 KB reduction scratch

    const int t = threadIdx.x;
    const int blocksPerMol = NA / JB;            // 64
    const int mol   = blockIdx.x / blocksPerMol;
    const int jBase = (blockIdx.x % blocksPerMol) * JB;
    const long molAtom = (long)mol * NA;

    for (int k = t; k < NA; k += BLOCK) {
        const long a = molAtom + k;
        sp4[k] = make_float4(pos[a*3+0], pos[a*3+1], pos[a*3+2], q[a]);
    }
    __syncthreads();

    const int jl  = t & (JL - 1);    // 0..7: j lane-group
    const int sid = t >> 3;          // 0..31: i-interleave slot
    const int j0  = jBase + jl;

    float4 jp[JT];
    int    jidx[JT];
    #pragma unroll
    for (int m = 0; m < JT; ++m) {
        jidx[m] = j0 + m * JL;
        jp[m]   = sp4[jidx[m]];
    }

    float acc[JT] = {0.0f, 0.0f, 0.0f, 0.0f};

    #pragma unroll 4
    for (int k = 0; k < NA / SPLIT; ++k) {
        const int i = k * SPLIT + sid;
        const float4 p = sp4[i];
        #pragma unroll
        for (int m = 0; m < JT; ++m) {
            float dx = p.x - jp[m].x;
            float dy = p.y - jp[m].y;
            float dz = p.z - jp[m].z;
            float d2 = fmaf(dx, dx, fmaf(dy, dy, fmaf(dz, dz, 1e-16f)));
            float inv = fast_rsqrt(d2);              // VALU-only, no trans
            float qs  = (i == jidx[m]) ? 0.0f : p.w; // diagonal mask
            acc[m] = fmaf(qs, inv, acc[m]);
        }
    }

    #pragma unroll
    for (int m = 0; m < JT; ++m)
        red[sid * RSTRIDE + jl + m * JL] = acc[m];
    __syncthreads();

    if (t < JB) {
        float field = 0.0f;
        #pragma unroll
        for (int s = 0; s < SPLIT; ++s) field += red[s * RSTRIDE + t];

        out[NB + molAtom + jBase + t] = field;          // q_field

        float pot = 0.5f * sp4[jBase + t].w * field;    // potential partial
        #pragma unroll
        for (int off = 16; off > 0; off >>= 1)
            pot += __shfl_down(pot, off, 32);
        if (t == 0) atomicAdd(&out[mol], pot);
    }
}

extern "C" void kernel_launch(void* const* d_in, const int* in_sizes, int n_in,
                              void* d_out, int out_size, void* d_ws, size_t ws_size,
                              hipStream_t stream) {
    const float* pos = (const float*)d_in[0];
    const float* q   = (const float*)d_in[1];
    float* out = (float*)d_out;

    zero_pot_kernel<<<1, 64, 0, stream>>>(out);

    const int grid = NB * (NA / JB);   // 1024 blocks -> 4 blocks/CU
    coulomb_kernel<<<grid, BLOCK, 0, stream>>>(pos, q, out);
}

// Round 18
// 81.851 us; speedup vs baseline: 1.0380x; 1.0380x over previous
//
#include <hip/hip_runtime.h>

#define NB 16        // molecules
#define NA 2048      // atoms per molecule
#define BLOCK 256
#define JL 8         // j lane-groups
#define JT 4         // j atoms per thread
#define JB (JL*JT)   // 32 j atoms per block
#define SPLIT 32     // i-interleave slots (= BLOCK/JL)

// Pack {x,y,z,q} into float4 workspace (fixes 12B-stride alignment) + zero pot.
__global__ void pack_zero_kernel(const float* __restrict__ pos,
                                 const float* __restrict__ q,
                                 float4* __restrict__ pk,
                                 float* __restrict__ out) {
    const int a = blockIdx.x * blockDim.x + threadIdx.x;   // 0..NB*NA-1
    pk[a] = make_float4(pos[a*3+0], pos[a*3+1], pos[a*3+2], q[a]);
    if (blockIdx.x == 0 && threadIdx.x < NB) out[threadIdx.x] = 0.0f;
}

// No big LDS: atoms read from global (0.5 MB, L2-resident; every block re-reads
// the same molecule stream). LDS = 512 B -> 8 blocks/CU = 8 waves/SIMD (2x R15).
__global__ __launch_bounds__(BLOCK) void coulomb_kernel(
    const float4* __restrict__ pk,   // [NB*NA] {x,y,z,q}
    float* __restrict__ out)         // [NB + NB*NA]
{
    __shared__ float red[4 * JB];    // 512 B: per-wave partials

    const int t = threadIdx.x;
    const int blocksPerMol = NA / JB;            // 64
    const int mol   = blockIdx.x / blocksPerMol;
    const int jBase = (blockIdx.x % blocksPerMol) * JB;
    const long molAtom = (long)mol * NA;
    const float4* mp = pk + molAtom;

    const int jl   = t & (JL - 1);   // 0..7
    const int sid  = t >> 3;         // 0..31: i-interleave slot
    const int wave = t >> 6;         // 0..3

    float4 jp[JT];
    int    jidx[JT];
    #pragma unroll
    for (int m = 0; m < JT; ++m) {
        jidx[m] = jBase + jl + m * JL;
        jp[m]   = mp[jidx[m]];       // 8 consecutive float4 per wave: coalesced
    }

    float acc[JT] = {0.0f, 0.0f, 0.0f, 0.0f};

    // Per wave per iter: 8 consecutive float4 (128 B = 2 lines, L2-hit),
    // broadcast to 8 lanes each. Unroll 4 gives 4 loads in flight.
    #pragma unroll 4
    for (int k = 0; k < NA / SPLIT; ++k) {
        const int i = k * SPLIT + sid;
        const float4 p = mp[i];
        #pragma unroll
        for (int m = 0; m < JT; ++m) {
            float dx = p.x - jp[m].x;
            float dy = p.y - jp[m].y;
            float dz = p.z - jp[m].z;
            float d2 = fmaf(dx, dx, fmaf(dy, dy, fmaf(dz, dz, 1e-16f)));
            float inv = __builtin_amdgcn_rsqf(d2);   // d2 >= 1e-16: finite
            float qs  = (i == jidx[m]) ? 0.0f : p.w; // diagonal mask
            acc[m] = fmaf(qs, inv, acc[m]);
        }
    }

    // In-wave butterfly across the wave's 8 sid groups (lanes stride 8):
    // afterwards every lane holds the wave-partial for its (jl, m).
    #pragma unroll
    for (int m = 0; m < JT; ++m) {
        acc[m] += __shfl_xor(acc[m], 8,  64);
        acc[m] += __shfl_xor(acc[m], 16, 64);
        acc[m] += __shfl_xor(acc[m], 32, 64);
    }
    if ((t & 63) < JL) {
        #pragma unroll
        for (int m = 0; m < JT; ++m)
            red[wave * JB + jl + m * JL] = acc[m];
    }
    __syncthreads();

    if (t < JB) {
        float field = red[t] + red[JB + t] + red[2*JB + t] + red[3*JB + t];

        out[NB + molAtom + jBase + t] = field;          // q_field

        float pot = 0.5f * mp[jBase + t].w * field;     // potential partial
        #pragma unroll
        for (int off = 16; off > 0; off >>= 1)
            pot += __shfl_down(pot, off, 32);           // lanes 0..31 segment
        if (t == 0) atomicAdd(&out[mol], pot);
    }
}

extern "C" void kernel_launch(void* const* d_in, const int* in_sizes, int n_in,
                              void* d_out, int out_size, void* d_ws, size_t ws_size,
                              hipStream_t stream) {
    const float* pos = (const float*)d_in[0];
    const float* q   = (const float*)d_in[1];
    float* out = (float*)d_out;
    float4* pk = (float4*)d_ws;      // 512 KB of the 256 MB workspace

    pack_zero_kernel<<<(NB * NA) / BLOCK, BLOCK, 0, stream>>>(pos, q, pk, out);

    const int grid = NB * (NA / JB);   // 1024 blocks -> 8 blocks/CU (thread-capped)
    coulomb_kernel<<<grid, BLOCK, 0, stream>>>(pk, out);
}